// Round 1
// baseline (8576.498 us; speedup 1.0000x reference)
//
#include <hip/hip_runtime.h>
#include <stdint.h>

typedef __bf16 bf16x8_t __attribute__((ext_vector_type(8)));
typedef float  f32x4_t  __attribute__((ext_vector_type(4)));

#define MFMA_BF16(A, Bv, C) __builtin_amdgcn_mfma_f32_16x16x32_bf16((A), (Bv), (C), 0, 0, 0)

static constexpr int BB = 16;      // batch
static constexpr int LL = 1024;    // seq len
static constexpr int DD = 2048;    // input dim
static constexpr int HH = 512;     // hidden
static constexpr int GG = 4 * HH;  // 2048 gate rows
static constexpr int MM = BB * LL; // 16384

// ---- workspace layout (bytes) ----
static constexpr size_t XBF_OFF   = 0;                                    // x bf16 [MM][DD]
static constexpr size_t WIHBF_OFF = XBF_OFF   + (size_t)MM * DD * 2;      // W_ih bf16 [GG][DD]
static constexpr size_t WHHBF_OFF = WIHBF_OFF + (size_t)GG * DD * 2;      // W_hh bf16 [GG][HH]
static constexpr size_t XGBF_OFF  = WHHBF_OFF + (size_t)GG * HH * 2;      // xg bf16 [MM][GG]
static constexpr size_t GARR_OFF  = XGBF_OFF  + (size_t)MM * GG * 2;      // g f32 [MM]
static constexpr size_t PART_OFF  = GARR_OFF  + (size_t)MM * 4;           // partials f32 [BB][8][HH]
static constexpr size_t HBUF_OFF  = PART_OFF  + (size_t)BB * 8 * HH * 4;  // h exchange bf16 [2][BB][HH]
static constexpr size_t CNT_OFF   = HBUF_OFF  + (size_t)2 * BB * HH * 2;  // barrier counters u32 [BB][LL]
static constexpr size_t WS_NEED   = CNT_OFF   + (size_t)BB * LL * 4;      // ~145.2 MB

__device__ __forceinline__ unsigned short f2bf(float f) {
  union { float f; uint32_t u; } v; v.f = f;
  uint32_t r = v.u + 0x7FFFu + ((v.u >> 16) & 1u);   // RNE
  return (unsigned short)(r >> 16);
}
__device__ __forceinline__ float bf2f(unsigned short s) {
  union { uint32_t u; float f; } v; v.u = ((uint32_t)s) << 16;
  return v.f;
}
__device__ __forceinline__ float sigmoidf_fast(float x) { return 1.f / (1.f + __expf(-x)); }
__device__ __forceinline__ float tanhf_fast(float x) {
  float ax = fabsf(x);
  float e  = __expf(2.f * ax);            // inf ok for large ax
  float t  = 1.f - 2.f / (e + 1.f);       // -> 1 as e -> inf
  return copysignf(t, x);
}
__device__ __forceinline__ void async_cp16(const void* g, void* lds) {
  __builtin_amdgcn_global_load_lds((const __attribute__((address_space(1))) uint32_t*)g,
                                   (__attribute__((address_space(3))) uint32_t*)lds, 16, 0, 0);
}

// ---------------- fp32 -> bf16 convert (vectorized) ----------------
__global__ __launch_bounds__(256) void k_f32_to_bf16(const float* __restrict__ s,
                                                     unsigned short* __restrict__ d, int n4) {
  int i = blockIdx.x * 256 + threadIdx.x;
  int stride = gridDim.x * 256;
  for (; i < n4; i += stride) {
    float4 v = ((const float4*)s)[i];
    ushort4 o;
    o.x = f2bf(v.x); o.y = f2bf(v.y); o.z = f2bf(v.z); o.w = f2bf(v.w);
    ((ushort4*)d)[i] = o;
  }
}

// ---------------- xg = x @ W_ih^T + (b_ih + b_hh), bf16 MFMA ----------------
// A = x bf16 [MM][DD] row-major, B = W_ih bf16 [GG][DD] row-major (i.e. B^T layout)
__global__ __launch_bounds__(256) void k_gemm_xg(const unsigned short* __restrict__ A,
                                                 const unsigned short* __restrict__ Bw,
                                                 const float* __restrict__ b_ih,
                                                 const float* __restrict__ b_hh,
                                                 unsigned short* __restrict__ C) {
  __shared__ __align__(16) unsigned short As[128 * 32];
  __shared__ __align__(16) unsigned short Bs[128 * 32];
  const int bid = blockIdx.x;
  const int bn = bid & 15, bm = bid >> 4;
  const int row0 = bm * 128, col0 = bn * 128;
  const int tid = threadIdx.x;
  const int lane = tid & 63, w = tid >> 6;
  const int wr = w >> 1, wc = w & 1;
  const int l15 = lane & 15, l4 = lane >> 4;

  const f32x4_t z4 = {0.f, 0.f, 0.f, 0.f};
  f32x4_t acc[4][4];
#pragma unroll
  for (int mi = 0; mi < 4; ++mi)
#pragma unroll
    for (int ni = 0; ni < 4; ++ni) acc[mi][ni] = z4;

  const unsigned short* ga = A  + (size_t)(row0 + (tid >> 2)) * DD + (tid & 3) * 8;
  const unsigned short* gb = Bw + (size_t)(col0 + (tid >> 2)) * DD + (tid & 3) * 8;
  unsigned short* asw = As + w * 512;   // wave-uniform LDS base (w*1024 bytes)
  unsigned short* bsw = Bs + w * 512;

  for (int k0 = 0; k0 < DD; k0 += 32) {
    async_cp16(ga + k0,           asw);          // rows 0..63
    async_cp16(ga + k0 + 64 * DD, asw + 2048);   // rows 64..127
    async_cp16(gb + k0,           bsw);
    async_cp16(gb + k0 + 64 * DD, bsw + 2048);
    __syncthreads();                              // drains vmcnt incl. global_load_lds
    bf16x8_t af[4], bfr[4];
#pragma unroll
    for (int mi = 0; mi < 4; ++mi)
      af[mi] = *(const bf16x8_t*)(As + (wr * 64 + mi * 16 + l15) * 32 + l4 * 8);
#pragma unroll
    for (int ni = 0; ni < 4; ++ni)
      bfr[ni] = *(const bf16x8_t*)(Bs + (wc * 64 + ni * 16 + l15) * 32 + l4 * 8);
#pragma unroll
    for (int mi = 0; mi < 4; ++mi)
#pragma unroll
      for (int ni = 0; ni < 4; ++ni)
        acc[mi][ni] = MFMA_BF16(af[mi], bfr[ni], acc[mi][ni]);
    __syncthreads();
  }
  // epilogue: + bias, store bf16.  D: col=lane&15, row=(lane>>4)*4+r  [m89]
#pragma unroll
  for (int ni = 0; ni < 4; ++ni) {
    int col = col0 + wc * 64 + ni * 16 + l15;
    float bias = b_ih[col] + b_hh[col];
#pragma unroll
    for (int mi = 0; mi < 4; ++mi) {
      int rowb = row0 + wr * 64 + mi * 16 + l4 * 4;
#pragma unroll
      for (int r = 0; r < 4; ++r)
        C[(size_t)(rowb + r) * GG + col] = f2bf(acc[mi][ni][r] + bias);
    }
  }
}

// ---------------- LSTM recurrence ----------------
// 16 independent sync domains (one per batch), 16 WGs each. Each WG owns h-slice
// [K0,K0+32); its 128 W_hh rows (i,f,g,o x 32) live in VGPRs as MFMA A-fragments.
// h exchanged per step via global bf16 double buffer + counter barrier.
// NOTE: 256 blocks x 256 thr, <=1-2 blocks/CU -> all co-resident on 256 CUs.
__global__ __launch_bounds__(256) void k_lstm(const unsigned short* __restrict__ Whh, // [GG][HH] bf16
                                              const unsigned short* __restrict__ xg,  // [MM][GG] bf16
                                              float* __restrict__ h_all,              // d_out [BB][LL][HH]
                                              unsigned short* __restrict__ h_buf,     // [2][BB][HH] bf16
                                              unsigned int* __restrict__ cnt) {       // [BB][LL]
  const int bid = blockIdx.x;
  const int b  = (bid & 7) + 8 * (bid >> 7);  // same-XCD grouping heuristic (correctness-independent)
  const int wg = (bid >> 3) & 15;
  const int tid = threadIdx.x;
  const int lane = tid & 63, w = tid >> 6;    // wave w handles gate w (0=i,1=f,2=g,3=o)
  const int l15 = lane & 15, l4 = lane >> 4;
  const int K0 = wg * 32;

  __shared__ float gl[4][32];

  // preload W_hh fragments: A[row][k], row=lane&15, k=(lane>>4)*8+j
  bf16x8_t wf[2][16];
#pragma unroll
  for (int mi = 0; mi < 2; ++mi) {
    const unsigned short* wrow = Whh + (size_t)(w * HH + K0 + mi * 16 + l15) * HH + l4 * 8;
#pragma unroll
    for (int kt = 0; kt < 16; ++kt)
      wf[mi][kt] = *(const bf16x8_t*)(wrow + kt * 32);
  }

  float c_reg = 0.f;
  unsigned int* mycnt = cnt + b * LL;
  const f32x4_t z4 = {0.f, 0.f, 0.f, 0.f};

  for (int t = 0; t < LL; ++t) {
    const int p = t & 1;
    // B operand: h broadcast into all 16 columns (identical columns -> any lane's D valid)
    const unsigned short* hb = h_buf + ((p * BB + b) << 9) + (l4 << 3);
    f32x4_t acc0 = z4, acc1 = z4;
#pragma unroll
    for (int kt = 0; kt < 16; ++kt) {
      bf16x8_t hv = *(const bf16x8_t*)(hb + (kt << 5));
      acc0 = MFMA_BF16(wf[0][kt], hv, acc0);
      acc1 = MFMA_BF16(wf[1][kt], hv, acc1);
    }
    if (l15 == 0) {
#pragma unroll
      for (int r = 0; r < 4; ++r) {
        gl[w][l4 * 4 + r]      = acc0[r];
        gl[w][16 + l4 * 4 + r] = acc1[r];
      }
    }
    __syncthreads();
    if (tid < 32) {   // pointwise cell update for this WG's 32 h elements (wave 0)
      const unsigned short* xr = xg + (size_t)((b << 10) + t) * GG + K0 + tid;
      float gi = sigmoidf_fast(gl[0][tid] + bf2f(xr[0]));
      float gf = sigmoidf_fast(gl[1][tid] + bf2f(xr[512]));
      float gc = tanhf_fast   (gl[2][tid] + bf2f(xr[1024]));
      float go = sigmoidf_fast(gl[3][tid] + bf2f(xr[1536]));
      c_reg = gf * c_reg + gi * gc;
      float h = go * tanhf_fast(c_reg);
      h_all[(size_t)((b << 10) + t) * HH + K0 + tid] = h;
      h_buf[(((1 - p) * BB + b) << 9) + K0 + tid] = f2bf(h);
    }
    if (tid == 0) {   // group barrier: release-add, relaxed spin, acquire fence
      __hip_atomic_fetch_add(mycnt + t, 1u, __ATOMIC_RELEASE, __HIP_MEMORY_SCOPE_AGENT);
      unsigned int guard = 0;
      while (__hip_atomic_load(mycnt + t, __ATOMIC_RELAXED, __HIP_MEMORY_SCOPE_AGENT) < 16u) {
        __builtin_amdgcn_s_sleep(1);
        if (++guard > (1u << 24)) break;   // failsafe: wrong-answer beats a hang
      }
      __threadfence();
    }
    __syncthreads();
  }
}

// ---------------- g = argmax(logits) as float ----------------
__global__ __launch_bounds__(256) void k_gsel(const float* __restrict__ h, const float* __restrict__ Wlin,
                                              const float* __restrict__ blin, float* __restrict__ g) {
  const int lane = threadIdx.x & 63, w = threadIdx.x >> 6;
  const int idx = blockIdx.x * 4 + w;
  const float4* hp = (const float4*)(h + (size_t)idx * HH + lane * 8);
  const float4* w0 = (const float4*)(Wlin + lane * 8);
  const float4* w1 = (const float4*)(Wlin + HH + lane * 8);
  float4 h0 = hp[0], h1 = hp[1];
  float4 a0 = w0[0], a1 = w0[1], c0 = w1[0], c1 = w1[1];
  float s0 = h0.x*a0.x + h0.y*a0.y + h0.z*a0.z + h0.w*a0.w
           + h1.x*a1.x + h1.y*a1.y + h1.z*a1.z + h1.w*a1.w;
  float s1 = h0.x*c0.x + h0.y*c0.y + h0.z*c0.z + h0.w*c0.w
           + h1.x*c1.x + h1.y*c1.y + h1.z*c1.z + h1.w*c1.w;
#pragma unroll
  for (int off = 32; off > 0; off >>= 1) {
    s0 += __shfl_xor(s0, off);
    s1 += __shfl_xor(s1, off);
  }
  if (lane == 0) g[idx] = (s1 + blin[1] > s0 + blin[0]) ? 1.f : 0.f;
}

// ---------------- scan phase A: per-(b,seg,k) partial sums of g*h ----------------
__global__ __launch_bounds__(256) void k_scan_a(const float* __restrict__ h, const float* __restrict__ g,
                                                float* __restrict__ part) {
  const int bid = blockIdx.x;
  const int b = bid >> 4, seg = (bid >> 1) & 7, kc = bid & 1;
  const int k = kc * 256 + threadIdx.x;
  __shared__ float gs[128];
  if (threadIdx.x < 128) gs[threadIdx.x] = g[b * LL + seg * 128 + threadIdx.x];
  __syncthreads();
  const float* hp = h + ((size_t)(b * LL + seg * 128)) * HH + k;
  float sum = 0.f;
#pragma unroll 4
  for (int l = 0; l < 128; ++l) sum += gs[l] * hp[(size_t)l * HH];
  part[(b * 8 + seg) * HH + k] = sum;
}

// ---------------- scan phase B: emit 2h + fa*S_excl + ba*(S_tot - S_incl) ----------------
__global__ __launch_bounds__(256) void k_scan_b(float* __restrict__ h, const float* __restrict__ g,
                                                const float* __restrict__ part,
                                                const float* __restrict__ fwd, const float* __restrict__ bwd) {
  const int bid = blockIdx.x;
  const int b = bid >> 4, seg = (bid >> 1) & 7, kc = bid & 1;
  const int k = kc * 256 + threadIdx.x;
  __shared__ float gs[128];
  if (threadIdx.x < 128) gs[threadIdx.x] = g[b * LL + seg * 128 + threadIdx.x];
  __syncthreads();
  float base = 0.f, total = 0.f;
#pragma unroll
  for (int s = 0; s < 8; ++s) {
    float v = part[(b * 8 + s) * HH + k];
    total += v;
    if (s < seg) base += v;
  }
  const float fa = fwd[k], ba = bwd[k];
  float run = base;
  float* hp = h + ((size_t)(b * LL + seg * 128)) * HH + k;
  for (int l = 0; l < 128; ++l) {
    float hv = hp[(size_t)l * HH];
    float term = gs[l] * hv;
    hp[(size_t)l * HH] = 2.f * hv + fa * run + ba * (total - run - term);
    run += term;
  }
}

extern "C" void kernel_launch(void* const* d_in, const int* in_sizes, int n_in,
                              void* d_out, int out_size, void* d_ws, size_t ws_size,
                              hipStream_t stream) {
  if (ws_size < WS_NEED) return;  // output stays poisoned -> visible failure, no corruption
  const float* x    = (const float*)d_in[0];
  const float* Wih  = (const float*)d_in[1];
  const float* Whh  = (const float*)d_in[2];
  const float* b_ih = (const float*)d_in[3];
  const float* b_hh = (const float*)d_in[4];
  const float* Wlin = (const float*)d_in[5];
  const float* blin = (const float*)d_in[6];
  const float* fwd  = (const float*)d_in[7];
  const float* bwd  = (const float*)d_in[8];
  char* ws = (char*)d_ws;
  unsigned short* xbf   = (unsigned short*)(ws + XBF_OFF);
  unsigned short* wihbf = (unsigned short*)(ws + WIHBF_OFF);
  unsigned short* whhbf = (unsigned short*)(ws + WHHBF_OFF);
  unsigned short* xgbf  = (unsigned short*)(ws + XGBF_OFF);
  float*          garr  = (float*)(ws + GARR_OFF);
  float*          part  = (float*)(ws + PART_OFF);
  unsigned short* hbuf  = (unsigned short*)(ws + HBUF_OFF);
  unsigned int*   cnt   = (unsigned int*)(ws + CNT_OFF);
  float* out = (float*)d_out;

  // zero h_buf (h0 = 0) and barrier counters every call (deterministic across replays)
  (void)hipMemsetAsync(ws + HBUF_OFF, 0, (size_t)(2 * BB * HH * 2) + (size_t)BB * LL * 4, stream);

  k_f32_to_bf16<<<2048, 256, 0, stream>>>(x,   xbf,   MM * DD / 4);
  k_f32_to_bf16<<<1024, 256, 0, stream>>>(Wih, wihbf, GG * DD / 4);
  k_f32_to_bf16<<<256,  256, 0, stream>>>(Whh, whhbf, GG * HH / 4);
  k_gemm_xg<<<(MM / 128) * (GG / 128), 256, 0, stream>>>(xbf, wihbf, b_ih, b_hh, xgbf);
  k_lstm<<<256, 256, 0, stream>>>(whhbf, xgbf, out, hbuf, cnt);
  k_gsel<<<MM / 4, 256, 0, stream>>>(out, Wlin, blin, garr);
  k_scan_a<<<256, 256, 0, stream>>>(out, garr, part);
  k_scan_b<<<256, 256, 0, stream>>>(out, garr, part, fwd, bwd);
}

// Round 2
// 1616.058 us; speedup vs baseline: 5.3071x; 5.3071x over previous
//
#include <hip/hip_runtime.h>
#include <stdint.h>

typedef __bf16 bf16x8_t __attribute__((ext_vector_type(8)));
typedef float  f32x4_t  __attribute__((ext_vector_type(4)));

#define MFMA_BF16(A, Bv, C) __builtin_amdgcn_mfma_f32_16x16x32_bf16((A), (Bv), (C), 0, 0, 0)

static constexpr int BB = 16;      // batch
static constexpr int LL = 1024;    // seq len
static constexpr int DD = 2048;    // input dim
static constexpr int HH = 512;     // hidden
static constexpr int GG = 4 * HH;  // 2048 gate rows
static constexpr int MM = BB * LL; // 16384

// ---- workspace layout (bytes) ----
static constexpr size_t XBF_OFF   = 0;                                    // x bf16 [MM][DD]
static constexpr size_t WIHBF_OFF = XBF_OFF   + (size_t)MM * DD * 2;      // W_ih bf16 [GG][DD]
static constexpr size_t WHHBF_OFF = WIHBF_OFF + (size_t)GG * DD * 2;      // W_hh bf16 [GG][HH]
static constexpr size_t XGBF_OFF  = WHHBF_OFF + (size_t)GG * HH * 2;      // xg bf16 [MM][GG]
static constexpr size_t GARR_OFF  = XGBF_OFF  + (size_t)MM * GG * 2;      // g f32 [MM]
static constexpr size_t PART_OFF  = GARR_OFF  + (size_t)MM * 4;           // partials f32 [BB][8][HH]
static constexpr size_t TBUF_OFF  = PART_OFF  + (size_t)BB * 8 * HH * 4;  // tagged h u32 [2][BB][HH]
static constexpr size_t WS_NEED   = TBUF_OFF  + (size_t)2 * BB * HH * 4;  // ~145.2 MB

__device__ __forceinline__ unsigned short f2bf(float f) {
  union { float f; uint32_t u; } v; v.f = f;
  uint32_t r = v.u + 0x7FFFu + ((v.u >> 16) & 1u);   // RNE
  return (unsigned short)(r >> 16);
}
__device__ __forceinline__ float bf2f(unsigned short s) {
  union { uint32_t u; float f; } v; v.u = ((uint32_t)s) << 16;
  return v.f;
}
__device__ __forceinline__ float sigmoidf_fast(float x) { return 1.f / (1.f + __expf(-x)); }
__device__ __forceinline__ float tanhf_fast(float x) {
  float ax = fabsf(x);
  float e  = __expf(2.f * ax);            // inf ok for large ax
  float t  = 1.f - 2.f / (e + 1.f);       // -> 1 as e -> inf
  return copysignf(t, x);
}
__device__ __forceinline__ void async_cp16(const void* g, void* lds) {
  __builtin_amdgcn_global_load_lds((const __attribute__((address_space(1))) uint32_t*)g,
                                   (__attribute__((address_space(3))) uint32_t*)lds, 16, 0, 0);
}

// ---------------- fp32 -> bf16 convert (vectorized) ----------------
__global__ __launch_bounds__(256) void k_f32_to_bf16(const float* __restrict__ s,
                                                     unsigned short* __restrict__ d, int n4) {
  int i = blockIdx.x * 256 + threadIdx.x;
  int stride = gridDim.x * 256;
  for (; i < n4; i += stride) {
    float4 v = ((const float4*)s)[i];
    ushort4 o;
    o.x = f2bf(v.x); o.y = f2bf(v.y); o.z = f2bf(v.z); o.w = f2bf(v.w);
    ((ushort4*)d)[i] = o;
  }
}

// ---------------- xg = x @ W_ih^T + (b_ih + b_hh), bf16 MFMA ----------------
__global__ __launch_bounds__(256) void k_gemm_xg(const unsigned short* __restrict__ A,
                                                 const unsigned short* __restrict__ Bw,
                                                 const float* __restrict__ b_ih,
                                                 const float* __restrict__ b_hh,
                                                 unsigned short* __restrict__ C) {
  __shared__ __align__(16) unsigned short As[128 * 32];
  __shared__ __align__(16) unsigned short Bs[128 * 32];
  const int bid = blockIdx.x;
  const int bn = bid & 15, bm = bid >> 4;
  const int row0 = bm * 128, col0 = bn * 128;
  const int tid = threadIdx.x;
  const int lane = tid & 63, w = tid >> 6;
  const int wr = w >> 1, wc = w & 1;
  const int l15 = lane & 15, l4 = lane >> 4;

  const f32x4_t z4 = {0.f, 0.f, 0.f, 0.f};
  f32x4_t acc[4][4];
#pragma unroll
  for (int mi = 0; mi < 4; ++mi)
#pragma unroll
    for (int ni = 0; ni < 4; ++ni) acc[mi][ni] = z4;

  const unsigned short* ga = A  + (size_t)(row0 + (tid >> 2)) * DD + (tid & 3) * 8;
  const unsigned short* gb = Bw + (size_t)(col0 + (tid >> 2)) * DD + (tid & 3) * 8;
  unsigned short* asw = As + w * 512;
  unsigned short* bsw = Bs + w * 512;

  for (int k0 = 0; k0 < DD; k0 += 32) {
    async_cp16(ga + k0,           asw);
    async_cp16(ga + k0 + 64 * DD, asw + 2048);
    async_cp16(gb + k0,           bsw);
    async_cp16(gb + k0 + 64 * DD, bsw + 2048);
    __syncthreads();
    bf16x8_t af[4], bfr[4];
#pragma unroll
    for (int mi = 0; mi < 4; ++mi)
      af[mi] = *(const bf16x8_t*)(As + (wr * 64 + mi * 16 + l15) * 32 + l4 * 8);
#pragma unroll
    for (int ni = 0; ni < 4; ++ni)
      bfr[ni] = *(const bf16x8_t*)(Bs + (wc * 64 + ni * 16 + l15) * 32 + l4 * 8);
#pragma unroll
    for (int mi = 0; mi < 4; ++mi)
#pragma unroll
      for (int ni = 0; ni < 4; ++ni)
        acc[mi][ni] = MFMA_BF16(af[mi], bfr[ni], acc[mi][ni]);
    __syncthreads();
  }
#pragma unroll
  for (int ni = 0; ni < 4; ++ni) {
    int col = col0 + wc * 64 + ni * 16 + l15;
    float bias = b_ih[col] + b_hh[col];
#pragma unroll
    for (int mi = 0; mi < 4; ++mi) {
      int rowb = row0 + wr * 64 + mi * 16 + l4 * 4;
#pragma unroll
      for (int r = 0; r < 4; ++r)
        C[(size_t)(rowb + r) * GG + col] = f2bf(acc[mi][ni][r] + bias);
    }
  }
}

// ---------------- LSTM recurrence ----------------
// 16 WGs per batch (one per 32-wide h-slice), fence-free tagged-data exchange:
// each h word published as (tag<<16)|bf16 via relaxed agent-scope store; consumers
// poll their own 2 words (one u64 load) until tags match, then stage h in LDS.
// h[t] lives in tbuf[(t+1)&1] with tag t+1; memset-0 == h[-1]=0 with tag 0.
__global__ __launch_bounds__(256) void k_lstm(const unsigned short* __restrict__ Whh, // [GG][HH] bf16
                                              const unsigned short* __restrict__ xg,  // [MM][GG] bf16
                                              float* __restrict__ h_all,              // d_out [BB][LL][HH]
                                              unsigned int* tbuf) {                   // [2][BB][HH] tagged u32
  const int bid = blockIdx.x;
  const int b  = (bid & 7) + 8 * (bid >> 7);  // same-XCD grouping heuristic
  const int wg = (bid >> 3) & 15;
  const int tid = threadIdx.x;
  const int lane = tid & 63, w = tid >> 6;    // wave w handles gate w (0=i,1=f,2=g,3=o)
  const int l15 = lane & 15, l4 = lane >> 4;
  const int K0 = wg * 32;

  __shared__ float gl[4][32];
  __shared__ __align__(16) unsigned short h_lds[HH];

  // preload W_hh fragments: A[row][k], row=lane&15, k=(lane>>4)*8+j
  bf16x8_t wf[2][16];
#pragma unroll
  for (int mi = 0; mi < 2; ++mi) {
    const unsigned short* wrow = Whh + (size_t)(w * HH + K0 + mi * 16 + l15) * HH + l4 * 8;
#pragma unroll
    for (int kt = 0; kt < 16; ++kt)
      wf[mi][kt] = *(const bf16x8_t*)(wrow + kt * 32);
  }

  float c_reg = 0.f;
  const f32x4_t z4 = {0.f, 0.f, 0.f, 0.f};

  // xg prefetch registers (meaningful for tid<32 only)
  float xgi = 0.f, xgf = 0.f, xgc = 0.f, xgo = 0.f;
  const unsigned short* xr0 = xg + (size_t)(b << 10) * GG + K0 + (tid & 31);
  if (tid < 32) {
    xgi = bf2f(xr0[0]); xgf = bf2f(xr0[512]); xgc = bf2f(xr0[1024]); xgo = bf2f(xr0[1536]);
  }

  for (int t = 0; t < LL; ++t) {
    // ---- poll this step's h (tag == t), words {2tid, 2tid+1}, one u64 load ----
    unsigned long long* src = (unsigned long long*)(tbuf + (((t & 1) * BB + b) << 9)) + tid;
    const unsigned int tg = (unsigned int)t;
    unsigned long long v;
    unsigned int guard = 0;
    for (;;) {
      v = __hip_atomic_load(src, __ATOMIC_RELAXED, __HIP_MEMORY_SCOPE_AGENT);
      if ((((unsigned int)(v >> 16) & 0xFFFFu) == tg) && ((unsigned int)(v >> 48) == tg)) break;
      if (++guard > (1u << 20)) break;   // failsafe: wrong-answer beats a hang
    }
    ushort2 hv2; hv2.x = (unsigned short)v; hv2.y = (unsigned short)(v >> 32);
    ((ushort2*)h_lds)[tid] = hv2;
    __syncthreads();

    // ---- gates: 2 MFMA chains, B = h broadcast in all 16 columns ----
    f32x4_t acc0 = z4, acc1 = z4;
#pragma unroll
    for (int kt = 0; kt < 16; ++kt) {
      bf16x8_t hv = *(const bf16x8_t*)(h_lds + kt * 32 + l4 * 8);
      acc0 = MFMA_BF16(wf[0][kt], hv, acc0);
      acc1 = MFMA_BF16(wf[1][kt], hv, acc1);
    }
    if (l15 == 0) {
#pragma unroll
      for (int r = 0; r < 4; ++r) {
        gl[w][l4 * 4 + r]      = acc0[r];
        gl[w][16 + l4 * 4 + r] = acc1[r];
      }
    }
    __syncthreads();

    // ---- pointwise cell update + publish (32 threads) ----
    if (tid < 32) {
      float gi = sigmoidf_fast(gl[0][tid] + xgi);
      float gf = sigmoidf_fast(gl[1][tid] + xgf);
      float gc = tanhf_fast   (gl[2][tid] + xgc);
      float go = sigmoidf_fast(gl[3][tid] + xgo);
      c_reg = gf * c_reg + gi * gc;
      float h = go * tanhf_fast(c_reg);
      unsigned int word = ((unsigned int)(t + 1) << 16) | (unsigned int)f2bf(h);
      unsigned int* dst = tbuf + ((((t + 1) & 1) * BB + b) << 9) + K0 + tid;
      __hip_atomic_store(dst, word, __ATOMIC_RELAXED, __HIP_MEMORY_SCOPE_AGENT);
      h_all[(size_t)((b << 10) + t) * HH + K0 + tid] = h;
      if (t + 1 < LL) {   // prefetch next step's xg into registers
        const unsigned short* xr = xr0 + (size_t)(t + 1) * GG;
        xgi = bf2f(xr[0]); xgf = bf2f(xr[512]); xgc = bf2f(xr[1024]); xgo = bf2f(xr[1536]);
      }
    }
  }
}

// ---------------- g = argmax(logits) as float ----------------
__global__ __launch_bounds__(256) void k_gsel(const float* __restrict__ h, const float* __restrict__ Wlin,
                                              const float* __restrict__ blin, float* __restrict__ g) {
  const int lane = threadIdx.x & 63, w = threadIdx.x >> 6;
  const int idx = blockIdx.x * 4 + w;
  const float4* hp = (const float4*)(h + (size_t)idx * HH + lane * 8);
  const float4* w0 = (const float4*)(Wlin + lane * 8);
  const float4* w1 = (const float4*)(Wlin + HH + lane * 8);
  float4 h0 = hp[0], h1 = hp[1];
  float4 a0 = w0[0], a1 = w0[1], c0 = w1[0], c1 = w1[1];
  float s0 = h0.x*a0.x + h0.y*a0.y + h0.z*a0.z + h0.w*a0.w
           + h1.x*a1.x + h1.y*a1.y + h1.z*a1.z + h1.w*a1.w;
  float s1 = h0.x*c0.x + h0.y*c0.y + h0.z*c0.z + h0.w*c0.w
           + h1.x*c1.x + h1.y*c1.y + h1.z*c1.z + h1.w*c1.w;
#pragma unroll
  for (int off = 32; off > 0; off >>= 1) {
    s0 += __shfl_xor(s0, off);
    s1 += __shfl_xor(s1, off);
  }
  if (lane == 0) g[idx] = (s1 + blin[1] > s0 + blin[0]) ? 1.f : 0.f;
}

// ---------------- scan phase A: per-(b,seg,k) partial sums of g*h ----------------
__global__ __launch_bounds__(256) void k_scan_a(const float* __restrict__ h, const float* __restrict__ g,
                                                float* __restrict__ part) {
  const int bid = blockIdx.x;
  const int b = bid >> 4, seg = (bid >> 1) & 7, kc = bid & 1;
  const int k = kc * 256 + threadIdx.x;
  __shared__ float gs[128];
  if (threadIdx.x < 128) gs[threadIdx.x] = g[b * LL + seg * 128 + threadIdx.x];
  __syncthreads();
  const float* hp = h + ((size_t)(b * LL + seg * 128)) * HH + k;
  float sum = 0.f;
#pragma unroll 4
  for (int l = 0; l < 128; ++l) sum += gs[l] * hp[(size_t)l * HH];
  part[(b * 8 + seg) * HH + k] = sum;
}

// ---------------- scan phase B: emit 2h + fa*S_excl + ba*(S_tot - S_incl) ----------------
__global__ __launch_bounds__(256) void k_scan_b(float* __restrict__ h, const float* __restrict__ g,
                                                const float* __restrict__ part,
                                                const float* __restrict__ fwd, const float* __restrict__ bwd) {
  const int bid = blockIdx.x;
  const int b = bid >> 4, seg = (bid >> 1) & 7, kc = bid & 1;
  const int k = kc * 256 + threadIdx.x;
  __shared__ float gs[128];
  if (threadIdx.x < 128) gs[threadIdx.x] = g[b * LL + seg * 128 + threadIdx.x];
  __syncthreads();
  float base = 0.f, total = 0.f;
#pragma unroll
  for (int s = 0; s < 8; ++s) {
    float v = part[(b * 8 + s) * HH + k];
    total += v;
    if (s < seg) base += v;
  }
  const float fa = fwd[k], ba = bwd[k];
  float run = base;
  float* hp = h + ((size_t)(b * LL + seg * 128)) * HH + k;
  for (int l = 0; l < 128; ++l) {
    float hv = hp[(size_t)l * HH];
    float term = gs[l] * hv;
    hp[(size_t)l * HH] = 2.f * hv + fa * run + ba * (total - run - term);
    run += term;
  }
}

extern "C" void kernel_launch(void* const* d_in, const int* in_sizes, int n_in,
                              void* d_out, int out_size, void* d_ws, size_t ws_size,
                              hipStream_t stream) {
  if (ws_size < WS_NEED) return;
  const float* x    = (const float*)d_in[0];
  const float* Wih  = (const float*)d_in[1];
  const float* Whh  = (const float*)d_in[2];
  const float* b_ih = (const float*)d_in[3];
  const float* b_hh = (const float*)d_in[4];
  const float* Wlin = (const float*)d_in[5];
  const float* blin = (const float*)d_in[6];
  const float* fwd  = (const float*)d_in[7];
  const float* bwd  = (const float*)d_in[8];
  char* ws = (char*)d_ws;
  unsigned short* xbf   = (unsigned short*)(ws + XBF_OFF);
  unsigned short* wihbf = (unsigned short*)(ws + WIHBF_OFF);
  unsigned short* whhbf = (unsigned short*)(ws + WHHBF_OFF);
  unsigned short* xgbf  = (unsigned short*)(ws + XGBF_OFF);
  float*          garr  = (float*)(ws + GARR_OFF);
  float*          part  = (float*)(ws + PART_OFF);
  unsigned int*   tbuf  = (unsigned int*)(ws + TBUF_OFF);
  float* out = (float*)d_out;

  // zero tagged h buffer: tag 0 == valid h[-1] = 0 (deterministic across graph replays)
  (void)hipMemsetAsync(ws + TBUF_OFF, 0, (size_t)2 * BB * HH * 4, stream);

  k_f32_to_bf16<<<2048, 256, 0, stream>>>(x,   xbf,   MM * DD / 4);
  k_f32_to_bf16<<<1024, 256, 0, stream>>>(Wih, wihbf, GG * DD / 4);
  k_f32_to_bf16<<<256,  256, 0, stream>>>(Whh, whhbf, GG * HH / 4);
  k_gemm_xg<<<(MM / 128) * (GG / 128), 256, 0, stream>>>(xbf, wihbf, b_ih, b_hh, xgbf);
  k_lstm<<<256, 256, 0, stream>>>(whhbf, xgbf, out, tbuf);
  k_gsel<<<MM / 4, 256, 0, stream>>>(out, Wlin, blin, garr);
  k_scan_a<<<256, 256, 0, stream>>>(out, garr, part);
  k_scan_b<<<256, 256, 0, stream>>>(out, garr, part, fwd, bwd);
}